// Round 7
// baseline (172.405 us; speedup 1.0000x reference)
//
#include <hip/hip_runtime.h>
#include <math.h>

#define NS 5000
#define SS 10
#define KK 20
#define HC 102
#define NBIN 32
#define BINW 16.0f
#define CAP 192          // per-wave candidate capacity (P(overflow) ~ 0 at R<=48)

// Wave-level LDS sync: drain LDS ops + compiler ordering. Waves own private
// LDS slices; no block barrier needed (escalation may diverge between waves).
#define WAVE_SYNC() __asm__ volatile("s_waitcnt lgkmcnt(0)" ::: "memory")

// ---------- Kernel 1 (single block, 1024 threads): stroke prep + full bin build ----------
// Fuses: bezier/rcp/color packing, bin counting, 1024-bin exclusive scan, CSR
// scatter. All counts/scan in LDS -> no global memset, 3 fewer dispatches.
// sdata[i][0..19] = bezier pts interleaved x,y; [20..28] = 1/|seg|^2; [29..31] pad
// ctab[i] = (r,g,b,width)
__global__ void __launch_bounds__(1024) build_kernel(
        const float* __restrict__ cs, const float* __restrict__ ce,
        const float* __restrict__ cc, const float* __restrict__ loc,
        const float* __restrict__ color, const float* __restrict__ width,
        float* __restrict__ sdata, float4* __restrict__ ctab,
        int* __restrict__ binStart, float2* __restrict__ sxy, int* __restrict__ sid) {
    __shared__ int cnt[NBIN*NBIN];
    __shared__ int wsum[16];
    int t = threadIdx.x;
    cnt[t] = 0;
    __syncthreads();

    // prep + count (strokes t, t+1024, ...)
    for (int i = t; i < NS; i += 1024) {
        float lx = loc[i*2+0], ly = loc[i*2+1];
        float sx = cs[i*2+0] + lx, sy = cs[i*2+1] + ly;
        float ex = ce[i*2+0] + lx, ey = ce[i*2+1] + ly;
        float px = cc[i*2+0] + lx, py = cc[i*2+1] + ly;
        float qx[SS], qy[SS];
        #pragma unroll
        for (int j = 0; j < SS; ++j) {
            float tt = (float)j * (1.0f / 9.0f);   // linspace(0,1,10) step in fp32
            float omt = 1.0f - tt;
            float omt2 = omt * omt, t2 = tt * tt;
            qx[j] = px + omt2 * (sx - px) + t2 * (ex - px);
            qy[j] = py + omt2 * (sy - py) + t2 * (ey - py);
            sdata[i*32 + 2*j + 0] = qx[j];
            sdata[i*32 + 2*j + 1] = qy[j];
        }
        #pragma unroll
        for (int sg = 0; sg < 9; ++sg) {
            float bx = qx[sg+1] - qx[sg], by = qy[sg+1] - qy[sg];
            sdata[i*32 + 20 + sg] = 1.0f / (bx*bx + by*by);   // full precision
        }
        sdata[i*32 + 29] = 0.0f; sdata[i*32 + 30] = 0.0f; sdata[i*32 + 31] = 0.0f;
        ctab[i] = make_float4(color[i*3+0], color[i*3+1], color[i*3+2], width[i]);
        int b0 = min(max((int)(lx * (1.0f/BINW)), 0), NBIN-1);
        int b1 = min(max((int)(ly * (1.0f/BINW)), 0), NBIN-1);
        atomicAdd(&cnt[b0*NBIN + b1], 1);
    }
    __syncthreads();

    // exclusive scan over 1024 bins: wave shuffle scan + cross-wave fixup
    int v = cnt[t];
    int lane = t & 63, w = t >> 6;
    int x = v;
    #pragma unroll
    for (int off = 1; off < 64; off <<= 1) {
        int y = __shfl_up(x, off, 64);
        if (lane >= off) x += y;
    }
    if (lane == 63) wsum[w] = x;
    __syncthreads();
    int woff = 0;
    #pragma unroll
    for (int i = 0; i < 16; ++i) woff += (i < w) ? wsum[i] : 0;
    int incl = woff + x;                 // inclusive prefix of bin t
    cnt[t] = incl - v;                   // exclusive start -> becomes atomic fill base
    binStart[t + 1] = incl;
    if (t == 0) binStart[0] = 0;
    __syncthreads();

    // scatter into CSR order
    for (int i = t; i < NS; i += 1024) {
        float l0 = loc[i*2+0], l1 = loc[i*2+1];
        int b0 = min(max((int)(l0 * (1.0f/BINW)), 0), NBIN-1);
        int b1 = min(max((int)(l1 * (1.0f/BINW)), 0), NBIN-1);
        int pos = atomicAdd(&cnt[b0*NBIN + b1], 1);
        sxy[pos] = make_float2(l0, l1);
        sid[pos] = i;
    }
}

// ---------- Kernel 2: per-cell top-20 via ballot compaction + rank selection ----------
// One wave per cell, 4 cells/block (grid = HC*HC/4 = 2601 exactly). Candidates
// with d<R^2 are ballot-compacted into wave-private LDS as (dist_bits<<32|idx)
// keys. Each lane computes its key's exact rank (# smaller keys) with an
// independent-iteration broadcast-read loop; ranks are a permutation (keys
// unique via idx low bits), so rank<20 lanes scatter straight to the output
// slot. Ascending distance, lower-index ties == jax.lax.top_k(-D, K) order.
// Exact: cnt>=20 inside radius R implies the global top-20 lie inside R.
__global__ void __launch_bounds__(256) topk_kernel(const float* __restrict__ loc,
                                                   const float* __restrict__ width,
                                                   const float2* __restrict__ sxy,
                                                   const int* __restrict__ sid,
                                                   const int* __restrict__ binStart,
                                                   int* __restrict__ idcs,
                                                   float* __restrict__ wk) {
    __shared__ unsigned long long sk[4][CAP];
    int w = threadIdx.x >> 6, lane = threadIdx.x & 63;
    int cell = blockIdx.x * 4 + w;                 // grid covers exactly HC*HC
    int ci = cell / HC, cj = cell - ci * HC;
    const float dc = 512.0f / 101.0f;              // linspace(0,512,102) step in fp32
    float c0 = (float)ci * dc;
    float c1 = (float)cj * dc;
    unsigned long long below = (1ull << lane) - 1ull;

    float R = 30.0f;                               // interior E[cnt] ~ 54
    int cnt = 0;
    for (int attempt = 0; attempt < 5; ++attempt) {
        float R2 = R * R;
        int base = 0;
        int by0 = max((int)((c0 - R) * (1.0f/BINW)), 0);
        int by1 = min((int)((c0 + R) * (1.0f/BINW)), NBIN-1);
        int bx0 = max((int)((c1 - R) * (1.0f/BINW)), 0);
        int bx1 = min((int)((c1 + R) * (1.0f/BINW)), NBIN-1);
        for (int by = by0; by <= by1; ++by) {
            int s = binStart[by*NBIN + bx0];
            int e = binStart[by*NBIN + bx1 + 1];   // bins in a row are contiguous
            for (int t0 = s; t0 < e; t0 += 64) {
                int t = t0 + lane;
                int tc = min(t, e - 1);
                float2 p = sxy[tc];
                float dx = c0 - p.x, dy = c1 - p.y;
                float d = dx*dx + dy*dy;
                bool pred = (t < e) && (d < R2);
                unsigned long long mask = __ballot(pred);
                int pos = base + __popcll(mask & below);
                if (pred && pos < CAP)
                    sk[w][pos] = ((unsigned long long)__float_as_uint(d) << 32)
                               | (unsigned int)sid[tc];
                base += __popcll(mask);
            }
        }
        cnt = base;
        if (cnt >= KK) break;                      // includes overflow -> fallback below
        R *= 1.6f;
    }
    WAVE_SYNC();

    if (cnt >= KK && cnt <= CAP) {
        if (cnt <= 64) {
            // common path (~92%): one key per lane
            unsigned long long k0 = (lane < cnt) ? sk[w][lane] : ~0ull;
            int r0 = 0;
            int j = 0;
            #pragma unroll 1
            for (; j + 4 <= cnt; j += 4) {
                unsigned long long a = sk[w][j],   b = sk[w][j+1];
                unsigned long long c = sk[w][j+2], d = sk[w][j+3];
                r0 += (int)(a < k0) + (int)(b < k0) + (int)(c < k0) + (int)(d < k0);
            }
            for (; j < cnt; ++j) r0 += (int)(sk[w][j] < k0);
            if (r0 < KK && lane < cnt) {
                int idx = (int)(unsigned int)(k0 & 0xffffffffull);
                idcs[cell*KK + r0] = idx;
                wk[cell*KK + r0]   = width[idx];
            }
        } else {
            // up to 3 keys per lane
            unsigned long long k0 = (lane       < cnt) ? sk[w][lane]       : ~0ull;
            unsigned long long k1 = (lane + 64  < cnt) ? sk[w][lane + 64]  : ~0ull;
            unsigned long long k2 = (lane + 128 < cnt) ? sk[w][lane + 128] : ~0ull;
            int r0 = 0, r1 = 0, r2 = 0;
            #pragma unroll 1
            for (int j = 0; j < cnt; ++j) {
                unsigned long long a = sk[w][j];
                r0 += (int)(a < k0); r1 += (int)(a < k1); r2 += (int)(a < k2);
            }
            if (r0 < KK && lane < cnt) {
                int idx = (int)(unsigned int)(k0 & 0xffffffffull);
                idcs[cell*KK + r0] = idx;  wk[cell*KK + r0] = width[idx];
            }
            if (r1 < KK && lane + 64 < cnt) {
                int idx = (int)(unsigned int)(k1 & 0xffffffffull);
                idcs[cell*KK + r1] = idx;  wk[cell*KK + r1] = width[idx];
            }
            if (r2 < KK && lane + 128 < cnt) {
                int idx = (int)(unsigned int)(k2 & 0xffffffffull);
                idcs[cell*KK + r2] = idx;  wk[cell*KK + r2] = width[idx];
            }
        }
    } else {
        // Exactness fallback (statistically never taken): serial top-K on lane 0.
        if (lane == 0) {
            float bd[KK]; int bi[KK];
            for (int k = 0; k < KK; ++k) { bd[k] = 3.4e38f; bi[k] = 0; }
            for (int n = 0; n < NS; ++n) {
                float dx = c0 - loc[n*2+0];
                float dy = c1 - loc[n*2+1];
                float d = dx*dx + dy*dy;
                if (d < bd[KK-1]) {
                    int p = KK - 1;
                    while (p > 0 && bd[p-1] > d) { bd[p] = bd[p-1]; bi[p] = bi[p-1]; --p; }
                    bd[p] = d; bi[p] = n;
                }
            }
            for (int k = 0; k < KK; ++k) {
                idcs[cell*KK + k] = bi[k];
                wk[cell*KK + k]   = width[bi[k]];
            }
        }
    }
}

// ---------- Kernel 3: full-res render, explicit software pipeline ----------
// Prefetch iteration k+1's stroke data into a second register set while
// computing iteration k: per-iter compute (~280 issue cycles) covers the
// ~200-cycle L2-hit gather latency. launch_bounds(256,4) caps VGPR at 128
// (grid gives only 16 waves/CU, so occupancy above 4 waves/EU is unreachable).
__global__ void __launch_bounds__(256, 4) render_kernel(const float* __restrict__ sdata,
                                                        const float4* __restrict__ ctab,
                                                        const int* __restrict__ idcs,
                                                        const float* __restrict__ wk,
                                                        float* __restrict__ out) {
    int x = blockIdx.x * 64 + threadIdx.x;   // wave = 64 contiguous x pixels
    int y = blockIdx.y * 4  + threadIdx.y;
    const float df = 512.0f / 511.0f;        // linspace(0,512,512) step in fp32
    float p0 = (float)y * df;                // H-coordinate
    float p1 = (float)x * df;                // W-coordinate
    int cy = (y * 51) >> 8;                  // floor(y*102/512), exact vs fp32 ref
    int cx = (x * 51) >> 8;

    // preload all 20 stroke indices (aligned: cell*20 ints = 80 B)
    const int4* mip = (const int4*)(idcs + (cy * HC + cx) * KK);
    int4 m0 = mip[0], m1 = mip[1], m2 = mip[2], m3 = mip[3], m4 = mip[4];
    int idxs[KK] = {m0.x,m0.y,m0.z,m0.w, m1.x,m1.y,m1.z,m1.w, m2.x,m2.y,m2.z,m2.w,
                    m3.x,m3.y,m3.z,m3.w, m4.x,m4.y,m4.z,m4.w};

    // jax.image.resize linear: half-pixel centers + edge-normalized == clamped bilinear
    const float sc = 102.0f / 512.0f;        // exact in fp32
    float iny = ((float)y + 0.5f) * sc - 0.5f;
    float inx = ((float)x + 0.5f) * sc - 0.5f;
    float y0f = floorf(iny), x0f = floorf(inx);
    float fy = iny - y0f, fx = inx - x0f;
    int y0 = min(max((int)y0f, 0), HC - 1);
    int y1 = min(max((int)y0f + 1, 0), HC - 1);
    int x0 = min(max((int)x0f, 0), HC - 1);
    int x1 = min(max((int)x0f + 1, 0), HC - 1);
    const float* w00 = wk + (y0 * HC + x0) * KK;
    const float* w01 = wk + (y0 * HC + x1) * KK;
    const float* w10 = wk + (y1 * HC + x0) * KK;
    const float* w11 = wk + (y1 * HC + x1) * KK;

    float m = -INFINITY, s = 0.0f;
    float a0 = 0.0f, a1 = 0.0f, a2 = 0.0f, wa = 0.0f;
    float D = INFINITY;

    // prefetch k=0
    const float4* sp = (const float4*)(sdata + idxs[0] * 32);
    float4 nf0 = sp[0], nf1 = sp[1], nf2 = sp[2], nf3 = sp[3], nf4 = sp[4];
    float4 ni0 = sp[5], ni1 = sp[6], ni2 = sp[7];
    float4 ncw = ctab[idxs[0]];

    #pragma unroll 1
    for (int k = 0; k < KK; ++k) {
        float4 f0 = nf0, f1 = nf1, f2 = nf2, f3 = nf3, f4 = nf4;
        float4 i0 = ni0, i1 = ni1, i2 = ni2;
        float4 cw = ncw;
        if (k + 1 < KK) {                         // issue next gathers early
            const float4* spn = (const float4*)(sdata + idxs[k+1] * 32);
            nf0 = spn[0]; nf1 = spn[1]; nf2 = spn[2]; nf3 = spn[3]; nf4 = spn[4];
            ni0 = spn[5]; ni1 = spn[6]; ni2 = spn[7];
            ncw = ctab[idxs[k+1]];
        }
        float qx[10] = {f0.x, f0.z, f1.x, f1.z, f2.x, f2.z, f3.x, f3.z, f4.x, f4.z};
        float qy[10] = {f0.y, f0.w, f1.y, f1.w, f2.y, f2.w, f3.y, f3.w, f4.y, f4.w};
        float iv[9]  = {i0.x, i0.y, i0.z, i0.w, i1.x, i1.y, i1.z, i1.w, i2.x};
        float mink = INFINITY;
        #pragma unroll
        for (int sg = 0; sg < 9; ++sg) {
            float ax = qx[sg], ay = qy[sg];
            float bx = qx[sg+1] - ax, by = qy[sg+1] - ay;
            float pax = p0 - ax, pay = p1 - ay;
            float dot = bx * pax + by * pay;
            float t = dot * iv[sg];
            t = fminf(fmaxf(t, 0.0f), 1.0f);
            float ccx = ax + t * bx, ccy = ay + t * by;
            float ddx = p0 - ccx, ddy = p1 - ccy;
            float d = ddx * ddx + ddy * ddy;
            mink = fminf(mink, d);
        }
        D = fminf(D, mink);
        float z = 100000.0f / (1e-8f + mink);    // keep IEEE div: softmax exponent is
                                                 // rounding-sensitive, matches passing rounds
        float wkv = (1.0f - fy) * ((1.0f - fx) * w00[k] + fx * w01[k])
                  +          fy * ((1.0f - fx) * w10[k] + fx * w11[k]);
        // branchless online softmax: numerically identical to branchy form
        float nm  = fmaxf(m, z);
        float scl = __expf(m - nm);              // m=-inf first iter -> 0
        float e   = __expf(z - nm);
        s  = s  * scl + e;
        a0 = a0 * scl + cw.x * e;
        a1 = a1 * scl + cw.y * e;
        a2 = a2 * scl + cw.z * e;
        wa = wa * scl + wkv  * e;
        m = nm;
    }
    float inv = 1.0f / s;
    float bs = wa * inv;
    float msk = 1.0f / (1.0f + __expf(-(bs - D)));   // sigmoid
    float o0 = a0 * inv * msk + (1.0f - msk) * 0.5f;
    float o1 = a1 * inv * msk + (1.0f - msk) * 0.5f;
    float o2 = a2 * inv * msk + (1.0f - msk) * 0.5f;
    int base = (y * 512 + x) * 3;
    out[base+0] = o0;
    out[base+1] = o1;
    out[base+2] = o2;
}

extern "C" void kernel_launch(void* const* d_in, const int* in_sizes, int n_in,
                              void* d_out, int out_size, void* d_ws, size_t ws_size,
                              hipStream_t stream) {
    const float* cs    = (const float*)d_in[0];  // curve_s (5000,2)
    const float* ce    = (const float*)d_in[1];  // curve_e (5000,2)
    const float* cc    = (const float*)d_in[2];  // curve_c (5000,2)
    const float* color = (const float*)d_in[3];  // color   (5000,3)
    const float* loc   = (const float*)d_in[4];  // location(5000,2)
    const float* width = (const float*)d_in[5];  // width   (5000,1)
    float* out = (float*)d_out;

    char* p = (char*)d_ws;
    float*  sdata    = (float*)p;                 p += NS * 32 * sizeof(float);       // 640000
    float4* ctab     = (float4*)p;                p += NS * sizeof(float4);           // 80000
    int*    idcs     = (int*)p;                   p += (size_t)HC*HC*KK*sizeof(int);  // 832320
    float*  wk       = (float*)p;                 p += (size_t)HC*HC*KK*sizeof(float);// 832320
    int*    binStart = (int*)p;                   p += 4112;                          // 1025 ints + pad
    float2* sxy      = (float2*)p;                p += NS * sizeof(float2);           // 40000
    int*    sid      = (int*)p;                   /* 20000 */

    build_kernel <<<1, 1024, 0, stream>>>(cs, ce, cc, loc, color, width,
                                          sdata, ctab, binStart, sxy, sid);
    topk_kernel  <<<(HC*HC)/4, 256, 0, stream>>>(loc, width, sxy, sid, binStart, idcs, wk);
    render_kernel<<<dim3(512/64, 512/4), dim3(64, 4), 0, stream>>>(sdata, ctab, idcs, wk, out);
}

// Round 11
// 134.110 us; speedup vs baseline: 1.2856x; 1.2856x over previous
//
#include <hip/hip_runtime.h>
#include <math.h>

#define NS 5000
#define SS 10
#define KK 20
#define HC 102
#define NBIN 32
#define BINW 16.0f
#define CAP 192          // per-wave candidate capacity (P(overflow) ~ 0 at R<=48)

// Wave-level LDS sync: drain LDS ops + compiler ordering. Waves own private
// LDS slices; no block barrier needed (escalation may diverge between waves).
#define WAVE_SYNC() __asm__ volatile("s_waitcnt lgkmcnt(0)" ::: "memory")

// ---------- Kernel 1: packed stroke data + color table + bin counts ----------
// (round-6 version, verbatim: passed twice)
__global__ void prep_kernel(const float* __restrict__ cs, const float* __restrict__ ce,
                            const float* __restrict__ cc, const float* __restrict__ loc,
                            const float* __restrict__ color, const float* __restrict__ width,
                            float* __restrict__ sdata, float4* __restrict__ ctab,
                            int* __restrict__ binCnt) {
    int i = blockIdx.x * 256 + threadIdx.x;
    if (i >= NS) return;
    float lx = loc[i*2+0], ly = loc[i*2+1];
    float sx = cs[i*2+0] + lx, sy = cs[i*2+1] + ly;
    float ex = ce[i*2+0] + lx, ey = ce[i*2+1] + ly;
    float px = cc[i*2+0] + lx, py = cc[i*2+1] + ly;
    float qx[SS], qy[SS];
    #pragma unroll
    for (int j = 0; j < SS; ++j) {
        float tt = (float)j * (1.0f / 9.0f);   // linspace(0,1,10) step in fp32
        float omt = 1.0f - tt;
        float omt2 = omt * omt, t2 = tt * tt;
        qx[j] = px + omt2 * (sx - px) + t2 * (ex - px);
        qy[j] = py + omt2 * (sy - py) + t2 * (ey - py);
        sdata[i*32 + 2*j + 0] = qx[j];
        sdata[i*32 + 2*j + 1] = qy[j];
    }
    #pragma unroll
    for (int sg = 0; sg < 9; ++sg) {
        float bx = qx[sg+1] - qx[sg], by = qy[sg+1] - qy[sg];
        sdata[i*32 + 20 + sg] = 1.0f / (bx*bx + by*by);   // full precision at prep time
    }
    sdata[i*32 + 29] = 0.0f; sdata[i*32 + 30] = 0.0f; sdata[i*32 + 31] = 0.0f;
    ctab[i] = make_float4(color[i*3+0], color[i*3+1], color[i*3+2], width[i]);
    int b0 = min(max((int)(lx * (1.0f/BINW)), 0), NBIN-1);
    int b1 = min(max((int)(ly * (1.0f/BINW)), 0), NBIN-1);
    atomicAdd(&binCnt[b0*NBIN + b1], 1);
}

// ---------- Kernel 2a: exclusive prefix over 1024 bins (round-6, verbatim) ----------
__global__ void binscan_kernel(const int* __restrict__ binCnt, int* __restrict__ binStart) {
    __shared__ int wsum[4];
    int t = threadIdx.x;                 // 0..255
    int lane = t & 63, w = t >> 6;
    int4 v = ((const int4*)binCnt)[t];
    int s0 = v.x, s1 = s0 + v.y, s2 = s1 + v.z, s3 = s2 + v.w;  // local inclusive
    int x = s3;
    #pragma unroll
    for (int off = 1; off < 64; off <<= 1) {
        int y = __shfl_up(x, off, 64);
        if (lane >= off) x += y;
    }
    if (lane == 63) wsum[w] = x;
    __syncthreads();
    int woff = 0;
    #pragma unroll
    for (int i = 0; i < 4; ++i) woff += (i < w) ? wsum[i] : 0;
    int texcl = woff + x - s3;           // exclusive prefix of this thread's 4 bins
    binStart[4*t+1] = texcl + s0;
    binStart[4*t+2] = texcl + s1;
    binStart[4*t+3] = texcl + s2;
    binStart[4*t+4] = texcl + s3;
    if (t == 0) binStart[0] = 0;
}

// ---------- Kernel 2b: scatter strokes into CSR order (round-6, verbatim) ----------
__global__ void binscatter_kernel(const float* __restrict__ loc, const int* __restrict__ binStart,
                                  int* __restrict__ binFill, float2* __restrict__ sxy,
                                  int* __restrict__ sid) {
    int i = blockIdx.x * 256 + threadIdx.x;
    if (i >= NS) return;
    float l0 = loc[i*2+0], l1 = loc[i*2+1];
    int b0 = min(max((int)(l0 * (1.0f/BINW)), 0), NBIN-1);
    int b1 = min(max((int)(l1 * (1.0f/BINW)), 0), NBIN-1);
    int b = b0*NBIN + b1;
    int pos = binStart[b] + atomicAdd(&binFill[b], 1);
    sxy[pos] = make_float2(l0, l1);
    sid[pos] = i;
}

// ---------- Kernel 3: per-cell top-20 (round-6, verbatim: exact, == jax.lax.top_k) ----------
__global__ void __launch_bounds__(256) topk_kernel(const float* __restrict__ loc,
                                                   const float* __restrict__ width,
                                                   const float2* __restrict__ sxy,
                                                   const int* __restrict__ sid,
                                                   const int* __restrict__ binStart,
                                                   int* __restrict__ idcs,
                                                   float* __restrict__ wk) {
    __shared__ unsigned long long sk[4][CAP];
    int w = threadIdx.x >> 6, lane = threadIdx.x & 63;
    int cell = blockIdx.x * 4 + w;                 // grid covers exactly HC*HC
    int ci = cell / HC, cj = cell - ci * HC;
    const float dc = 512.0f / 101.0f;              // linspace(0,512,102) step in fp32
    float c0 = (float)ci * dc;
    float c1 = (float)cj * dc;
    unsigned long long below = (1ull << lane) - 1ull;

    float R = 30.0f;                               // interior E[cnt] ~ 54
    int cnt = 0;
    for (int attempt = 0; attempt < 5; ++attempt) {
        float R2 = R * R;
        int base = 0;
        int by0 = max((int)((c0 - R) * (1.0f/BINW)), 0);
        int by1 = min((int)((c0 + R) * (1.0f/BINW)), NBIN-1);
        int bx0 = max((int)((c1 - R) * (1.0f/BINW)), 0);
        int bx1 = min((int)((c1 + R) * (1.0f/BINW)), NBIN-1);
        for (int by = by0; by <= by1; ++by) {
            int s = binStart[by*NBIN + bx0];
            int e = binStart[by*NBIN + bx1 + 1];   // bins in a row are contiguous
            for (int t0 = s; t0 < e; t0 += 64) {
                int t = t0 + lane;
                int tc = min(t, e - 1);
                float2 p = sxy[tc];
                float dx = c0 - p.x, dy = c1 - p.y;
                float d = dx*dx + dy*dy;
                bool pred = (t < e) && (d < R2);
                unsigned long long mask = __ballot(pred);
                int pos = base + __popcll(mask & below);
                if (pred && pos < CAP)
                    sk[w][pos] = ((unsigned long long)__float_as_uint(d) << 32)
                               | (unsigned int)sid[tc];
                base += __popcll(mask);
            }
        }
        cnt = base;
        if (cnt >= KK) break;                      // includes overflow -> fallback below
        R *= 1.6f;
    }
    WAVE_SYNC();

    if (cnt >= KK && cnt <= CAP) {
        if (cnt <= 64) {
            unsigned long long k0 = (lane < cnt) ? sk[w][lane] : ~0ull;
            int r0 = 0;
            int j = 0;
            #pragma unroll 1
            for (; j + 4 <= cnt; j += 4) {
                unsigned long long a = sk[w][j],   b = sk[w][j+1];
                unsigned long long c = sk[w][j+2], d = sk[w][j+3];
                r0 += (int)(a < k0) + (int)(b < k0) + (int)(c < k0) + (int)(d < k0);
            }
            for (; j < cnt; ++j) r0 += (int)(sk[w][j] < k0);
            if (r0 < KK && lane < cnt) {
                int idx = (int)(unsigned int)(k0 & 0xffffffffull);
                idcs[cell*KK + r0] = idx;
                wk[cell*KK + r0]   = width[idx];
            }
        } else {
            unsigned long long k0 = (lane       < cnt) ? sk[w][lane]       : ~0ull;
            unsigned long long k1 = (lane + 64  < cnt) ? sk[w][lane + 64]  : ~0ull;
            unsigned long long k2 = (lane + 128 < cnt) ? sk[w][lane + 128] : ~0ull;
            int r0 = 0, r1 = 0, r2 = 0;
            #pragma unroll 1
            for (int j = 0; j < cnt; ++j) {
                unsigned long long a = sk[w][j];
                r0 += (int)(a < k0); r1 += (int)(a < k1); r2 += (int)(a < k2);
            }
            if (r0 < KK && lane < cnt) {
                int idx = (int)(unsigned int)(k0 & 0xffffffffull);
                idcs[cell*KK + r0] = idx;  wk[cell*KK + r0] = width[idx];
            }
            if (r1 < KK && lane + 64 < cnt) {
                int idx = (int)(unsigned int)(k1 & 0xffffffffull);
                idcs[cell*KK + r1] = idx;  wk[cell*KK + r1] = width[idx];
            }
            if (r2 < KK && lane + 128 < cnt) {
                int idx = (int)(unsigned int)(k2 & 0xffffffffull);
                idcs[cell*KK + r2] = idx;  wk[cell*KK + r2] = width[idx];
            }
        }
    } else {
        if (lane == 0) {                 // exactness fallback (statistically never)
            float bd[KK]; int bi[KK];
            for (int k = 0; k < KK; ++k) { bd[k] = 3.4e38f; bi[k] = 0; }
            for (int n = 0; n < NS; ++n) {
                float dx = c0 - loc[n*2+0];
                float dy = c1 - loc[n*2+1];
                float d = dx*dx + dy*dy;
                if (d < bd[KK-1]) {
                    int p = KK - 1;
                    while (p > 0 && bd[p-1] > d) { bd[p] = bd[p-1]; bi[p] = bi[p-1]; --p; }
                    bd[p] = d; bi[p] = n;
                }
            }
            for (int k = 0; k < KK; ++k) {
                idcs[cell*KK + k] = bi[k];
                wk[cell*KK + k]   = width[bi[k]];
            }
        }
    }
}

// ---------- Kernel 4: render — round-6 body verbatim; ONLY the thread->pixel ----------
// mapping changed to 8x8 wave tiles (bisection variable). In-loop wkv gathers,
// unroll 4, branchless softmax: all exactly as the passing round-6 kernel.
__global__ void __launch_bounds__(256, 4) render_kernel(const float* __restrict__ sdata,
                                                        const float4* __restrict__ ctab,
                                                        const int* __restrict__ idcs,
                                                        const float* __restrict__ wk,
                                                        float* __restrict__ out) {
    int tt0 = threadIdx.x, lane = tt0 & 63, wq = tt0 >> 6;
    int x = blockIdx.x * 16 + ((wq & 1) << 3) + (lane & 7);   // wave = 8x8 pixel tile
    int y = blockIdx.y * 16 + ((wq >> 1) << 3) + (lane >> 3);
    const float df = 512.0f / 511.0f;        // linspace(0,512,512) step in fp32
    float p0 = (float)y * df;                // H-coordinate
    float p1 = (float)x * df;                // W-coordinate
    int cy = (y * 51) >> 8;                  // floor(y*102/512), exact vs fp32 ref
    int cx = (x * 51) >> 8;

    // preload all 20 stroke indices (aligned: cell*20 ints = 80 B)
    const int4* mip = (const int4*)(idcs + (cy * HC + cx) * KK);
    int4 m0 = mip[0], m1 = mip[1], m2 = mip[2], m3 = mip[3], m4 = mip[4];
    int idxs[KK] = {m0.x,m0.y,m0.z,m0.w, m1.x,m1.y,m1.z,m1.w, m2.x,m2.y,m2.z,m2.w,
                    m3.x,m3.y,m3.z,m3.w, m4.x,m4.y,m4.z,m4.w};

    // jax.image.resize linear: half-pixel centers + edge-normalized == clamped bilinear
    const float sc = 102.0f / 512.0f;        // exact in fp32
    float iny = ((float)y + 0.5f) * sc - 0.5f;
    float inx = ((float)x + 0.5f) * sc - 0.5f;
    float y0f = floorf(iny), x0f = floorf(inx);
    float fy = iny - y0f, fx = inx - x0f;
    int y0 = min(max((int)y0f, 0), HC - 1);
    int y1 = min(max((int)y0f + 1, 0), HC - 1);
    int x0 = min(max((int)x0f, 0), HC - 1);
    int x1 = min(max((int)x0f + 1, 0), HC - 1);
    const float* w00 = wk + (y0 * HC + x0) * KK;
    const float* w01 = wk + (y0 * HC + x1) * KK;
    const float* w10 = wk + (y1 * HC + x0) * KK;
    const float* w11 = wk + (y1 * HC + x1) * KK;

    float m = -INFINITY, s = 0.0f;
    float a0 = 0.0f, a1 = 0.0f, a2 = 0.0f, wa = 0.0f;
    float D = INFINITY;

    #pragma unroll 4
    for (int k = 0; k < KK; ++k) {
        const float4* sp = (const float4*)(sdata + idxs[k] * 32);
        float4 f0 = sp[0], f1 = sp[1], f2 = sp[2], f3 = sp[3], f4 = sp[4];
        float4 i0 = sp[5], i1 = sp[6], i2 = sp[7];
        float4 cw = ctab[idxs[k]];
        float qx[10] = {f0.x, f0.z, f1.x, f1.z, f2.x, f2.z, f3.x, f3.z, f4.x, f4.z};
        float qy[10] = {f0.y, f0.w, f1.y, f1.w, f2.y, f2.w, f3.y, f3.w, f4.y, f4.w};
        float iv[9]  = {i0.x, i0.y, i0.z, i0.w, i1.x, i1.y, i1.z, i1.w, i2.x};
        float mink = INFINITY;
        #pragma unroll
        for (int sg = 0; sg < 9; ++sg) {
            float ax = qx[sg], ay = qy[sg];
            float bx = qx[sg+1] - ax, by = qy[sg+1] - ay;
            float pax = p0 - ax, pay = p1 - ay;
            float dot = bx * pax + by * pay;
            float tt = dot * iv[sg];
            tt = fminf(fmaxf(tt, 0.0f), 1.0f);
            float ccx = ax + tt * bx, ccy = ay + tt * by;
            float ddx = p0 - ccx, ddy = p1 - ccy;
            float d = ddx * ddx + ddy * ddy;
            mink = fminf(mink, d);
        }
        D = fminf(D, mink);
        float z = 100000.0f / (1e-8f + mink);    // IEEE div: exponent is rounding-sensitive
        float wkv = (1.0f - fy) * ((1.0f - fx) * w00[k] + fx * w01[k])
                  +          fy * ((1.0f - fx) * w10[k] + fx * w11[k]);
        // branchless online softmax (== subtract-max softmax, exp(0)==1 exactly)
        float nm  = fmaxf(m, z);
        float scl = __expf(m - nm);              // m=-inf first iter -> 0
        float e   = __expf(z - nm);
        s  = s  * scl + e;
        a0 = a0 * scl + cw.x * e;
        a1 = a1 * scl + cw.y * e;
        a2 = a2 * scl + cw.z * e;
        wa = wa * scl + wkv  * e;
        m = nm;
    }
    float inv = 1.0f / s;
    float bs = wa * inv;
    float msk = 1.0f / (1.0f + __expf(-(bs - D)));   // sigmoid
    float o0 = a0 * inv * msk + (1.0f - msk) * 0.5f;
    float o1 = a1 * inv * msk + (1.0f - msk) * 0.5f;
    float o2 = a2 * inv * msk + (1.0f - msk) * 0.5f;
    int base = (y * 512 + x) * 3;
    out[base+0] = o0;
    out[base+1] = o1;
    out[base+2] = o2;
}

extern "C" void kernel_launch(void* const* d_in, const int* in_sizes, int n_in,
                              void* d_out, int out_size, void* d_ws, size_t ws_size,
                              hipStream_t stream) {
    const float* cs    = (const float*)d_in[0];  // curve_s (5000,2)
    const float* ce    = (const float*)d_in[1];  // curve_e (5000,2)
    const float* cc    = (const float*)d_in[2];  // curve_c (5000,2)
    const float* color = (const float*)d_in[3];  // color   (5000,3)
    const float* loc   = (const float*)d_in[4];  // location(5000,2)
    const float* width = (const float*)d_in[5];  // width   (5000,1)
    float* out = (float*)d_out;

    char* p = (char*)d_ws;
    float*  sdata    = (float*)p;                 p += NS * 32 * sizeof(float);       // 640000
    float4* ctab     = (float4*)p;                p += NS * sizeof(float4);           // 80000
    int*    idcs     = (int*)p;                   p += (size_t)HC*HC*KK*sizeof(int);  // 832320
    float*  wk       = (float*)p;                 p += (size_t)HC*HC*KK*sizeof(float);// 832320
    int*    binCnt   = (int*)p;                   p += NBIN*NBIN*sizeof(int);         // 4096
    int*    binFill  = (int*)p;                   p += NBIN*NBIN*sizeof(int);         // 4096
    int*    binStart = (int*)p;                   p += 4112;                          // 1025 ints + pad
    float2* sxy      = (float2*)p;                p += NS * sizeof(float2);           // 40000
    int*    sid      = (int*)p;                   /* 20000 */

    hipMemsetAsync(binCnt, 0, 2 * NBIN * NBIN * sizeof(int), stream);  // binCnt + binFill

    prep_kernel      <<<(NS + 255) / 256, 256, 0, stream>>>(cs, ce, cc, loc, color, width,
                                                            sdata, ctab, binCnt);
    binscan_kernel   <<<1, 256, 0, stream>>>(binCnt, binStart);
    binscatter_kernel<<<(NS + 255) / 256, 256, 0, stream>>>(loc, binStart, binFill, sxy, sid);
    topk_kernel      <<<(HC*HC)/4, 256, 0, stream>>>(loc, width, sxy, sid, binStart, idcs, wk);
    render_kernel    <<<dim3(32, 32), 256, 0, stream>>>(sdata, ctab, idcs, wk, out);
}

// Round 12
// 131.592 us; speedup vs baseline: 1.3102x; 1.0191x over previous
//
#include <hip/hip_runtime.h>
#include <math.h>

#define NS 5000
#define SS 10
#define KK 20
#define HC 102
#define NBIN 32
#define BINW 16.0f
#define NPB 20           // prep/scatter blocks: ceil(5000/256)
#define CAP 192          // per-wave candidate capacity (P(overflow) ~ 0 at R<=48)

// Wave-level LDS sync: drain LDS ops + compiler ordering. Waves own private
// LDS slices; no block barrier needed (escalation may diverge between waves).
#define WAVE_SYNC() __asm__ volatile("s_waitcnt lgkmcnt(0)" ::: "memory")

// ---------- Kernel 1: stroke records + per-block bin counts (no global memset) ----------
// sdata layout (32 floats): [0..19] bezier pts xy, [20..28] 1/|seg|^2, [29..31] pad
// ctab[i] = (r,g,b,width). Per-block counts -> binCntP slice (no global atomics).
__global__ void __launch_bounds__(256) prep_kernel(
        const float* __restrict__ cs, const float* __restrict__ ce,
        const float* __restrict__ cc, const float* __restrict__ loc,
        const float* __restrict__ color, const float* __restrict__ width,
        float* __restrict__ sdata, float4* __restrict__ ctab,
        int* __restrict__ binCntP) {
    __shared__ int4 lcnt4[NBIN*NBIN/4];          // int4 decl guarantees 16B alignment
    int* lcnt = (int*)lcnt4;
    int t = threadIdx.x;
    lcnt4[t] = make_int4(0, 0, 0, 0);
    __syncthreads();
    int i = blockIdx.x * 256 + t;
    if (i < NS) {
        float lx = loc[i*2+0], ly = loc[i*2+1];
        float sx = cs[i*2+0] + lx, sy = cs[i*2+1] + ly;
        float ex = ce[i*2+0] + lx, ey = ce[i*2+1] + ly;
        float px = cc[i*2+0] + lx, py = cc[i*2+1] + ly;
        float qx[SS], qy[SS];
        #pragma unroll
        for (int j = 0; j < SS; ++j) {
            float tt = (float)j * (1.0f / 9.0f);   // linspace(0,1,10) step in fp32
            float omt = 1.0f - tt;
            float omt2 = omt * omt, t2 = tt * tt;
            qx[j] = px + omt2 * (sx - px) + t2 * (ex - px);
            qy[j] = py + omt2 * (sy - py) + t2 * (ey - py);
            sdata[i*32 + 2*j + 0] = qx[j];
            sdata[i*32 + 2*j + 1] = qy[j];
        }
        #pragma unroll
        for (int sg = 0; sg < 9; ++sg) {
            float bx = qx[sg+1] - qx[sg], by = qy[sg+1] - qy[sg];
            sdata[i*32 + 20 + sg] = 1.0f / (bx*bx + by*by);   // full precision
        }
        sdata[i*32 + 29] = 0.0f; sdata[i*32 + 30] = 0.0f; sdata[i*32 + 31] = 0.0f;
        ctab[i] = make_float4(color[i*3+0], color[i*3+1], color[i*3+2], width[i]);
        int b0 = min(max((int)(lx * (1.0f/BINW)), 0), NBIN-1);
        int b1 = min(max((int)(ly * (1.0f/BINW)), 0), NBIN-1);
        atomicAdd(&lcnt[b0*NBIN + b1], 1);
    }
    __syncthreads();
    ((int4*)binCntP)[blockIdx.x * 256 + t] = lcnt4[t];
}

// ---------- Kernel 2: redundant per-block scan + CSR scatter (no binscan dispatch) ----------
// Each of the 20 blocks sums all 20 per-block count slices (tracking the prefix
// over lower block ids), scans the 1024 bins, then places its own strokes at
// globalStart[bin] + below[bin] + LDS-atomic rank. Block 0 publishes binStart.
// Positions globally unique by construction. Proven bit-equivalent to the
// memset+binscan+binscatter pipeline (r9/r10 bisection evidence).
__global__ void __launch_bounds__(256) scatter_kernel(
        const float* __restrict__ loc, const int* __restrict__ binCntP,
        int* __restrict__ binStart, float2* __restrict__ sxy, int* __restrict__ sid) {
    __shared__ int fill[NBIN*NBIN];
    __shared__ int wsum[4];
    int t = threadIdx.x, lane = t & 63, w = t >> 6;
    int mb = blockIdx.x;
    int4 tot = make_int4(0,0,0,0), bel = make_int4(0,0,0,0);
    for (int b = 0; b < NPB; ++b) {
        int4 v = ((const int4*)binCntP)[b * 256 + t];
        tot.x += v.x; tot.y += v.y; tot.z += v.z; tot.w += v.w;
        if (b < mb) { bel.x += v.x; bel.y += v.y; bel.z += v.z; bel.w += v.w; }
    }
    int s0 = tot.x, s1 = s0 + tot.y, s2 = s1 + tot.z, s3 = s2 + tot.w;
    int x = s3;
    #pragma unroll
    for (int off = 1; off < 64; off <<= 1) {
        int y = __shfl_up(x, off, 64);
        if (lane >= off) x += y;
    }
    if (lane == 63) wsum[w] = x;
    __syncthreads();
    int woff = 0;
    #pragma unroll
    for (int i = 0; i < 4; ++i) woff += (i < w) ? wsum[i] : 0;
    int texcl = woff + x - s3;           // exclusive prefix of this thread's 4 bins
    fill[4*t+0] = texcl      + bel.x;
    fill[4*t+1] = texcl + s0 + bel.y;
    fill[4*t+2] = texcl + s1 + bel.z;
    fill[4*t+3] = texcl + s2 + bel.w;
    if (mb == 0) {                       // publish global scan for topk
        binStart[4*t+1] = texcl + s0;
        binStart[4*t+2] = texcl + s1;
        binStart[4*t+3] = texcl + s2;
        binStart[4*t+4] = texcl + s3;
        if (t == 0) binStart[0] = 0;
    }
    __syncthreads();
    int i = mb * 256 + t;
    if (i < NS) {
        float l0 = loc[i*2+0], l1 = loc[i*2+1];
        int b0 = min(max((int)(l0 * (1.0f/BINW)), 0), NBIN-1);
        int b1 = min(max((int)(l1 * (1.0f/BINW)), 0), NBIN-1);
        int pos = atomicAdd(&fill[b0*NBIN + b1], 1);
        sxy[pos] = make_float2(l0, l1);
        sid[pos] = i;
    }
}

// ---------- Kernel 3: per-cell top-20 (r11 verbatim: exact, == jax.lax.top_k) ----------
__global__ void __launch_bounds__(256) topk_kernel(const float* __restrict__ loc,
                                                   const float* __restrict__ width,
                                                   const float2* __restrict__ sxy,
                                                   const int* __restrict__ sid,
                                                   const int* __restrict__ binStart,
                                                   int* __restrict__ idcs,
                                                   float* __restrict__ wk) {
    __shared__ unsigned long long sk[4][CAP];
    int w = threadIdx.x >> 6, lane = threadIdx.x & 63;
    int cell = blockIdx.x * 4 + w;                 // grid covers exactly HC*HC
    int ci = cell / HC, cj = cell - ci * HC;
    const float dc = 512.0f / 101.0f;              // linspace(0,512,102) step in fp32
    float c0 = (float)ci * dc;
    float c1 = (float)cj * dc;
    unsigned long long below = (1ull << lane) - 1ull;

    float R = 30.0f;                               // interior E[cnt] ~ 54
    int cnt = 0;
    for (int attempt = 0; attempt < 5; ++attempt) {
        float R2 = R * R;
        int base = 0;
        int by0 = max((int)((c0 - R) * (1.0f/BINW)), 0);
        int by1 = min((int)((c0 + R) * (1.0f/BINW)), NBIN-1);
        int bx0 = max((int)((c1 - R) * (1.0f/BINW)), 0);
        int bx1 = min((int)((c1 + R) * (1.0f/BINW)), NBIN-1);
        for (int by = by0; by <= by1; ++by) {
            int s = binStart[by*NBIN + bx0];
            int e = binStart[by*NBIN + bx1 + 1];   // bins in a row are contiguous
            for (int t0 = s; t0 < e; t0 += 64) {
                int t = t0 + lane;
                int tc = min(t, e - 1);
                float2 p = sxy[tc];
                float dx = c0 - p.x, dy = c1 - p.y;
                float d = dx*dx + dy*dy;
                bool pred = (t < e) && (d < R2);
                unsigned long long mask = __ballot(pred);
                int pos = base + __popcll(mask & below);
                if (pred && pos < CAP)
                    sk[w][pos] = ((unsigned long long)__float_as_uint(d) << 32)
                               | (unsigned int)sid[tc];
                base += __popcll(mask);
            }
        }
        cnt = base;
        if (cnt >= KK) break;                      // includes overflow -> fallback below
        R *= 1.6f;
    }
    WAVE_SYNC();

    if (cnt >= KK && cnt <= CAP) {
        if (cnt <= 64) {
            unsigned long long k0 = (lane < cnt) ? sk[w][lane] : ~0ull;
            int r0 = 0;
            int j = 0;
            #pragma unroll 1
            for (; j + 4 <= cnt; j += 4) {
                unsigned long long a = sk[w][j],   b = sk[w][j+1];
                unsigned long long c = sk[w][j+2], d = sk[w][j+3];
                r0 += (int)(a < k0) + (int)(b < k0) + (int)(c < k0) + (int)(d < k0);
            }
            for (; j < cnt; ++j) r0 += (int)(sk[w][j] < k0);
            if (r0 < KK && lane < cnt) {
                int idx = (int)(unsigned int)(k0 & 0xffffffffull);
                idcs[cell*KK + r0] = idx;
                wk[cell*KK + r0]   = width[idx];
            }
        } else {
            unsigned long long k0 = (lane       < cnt) ? sk[w][lane]       : ~0ull;
            unsigned long long k1 = (lane + 64  < cnt) ? sk[w][lane + 64]  : ~0ull;
            unsigned long long k2 = (lane + 128 < cnt) ? sk[w][lane + 128] : ~0ull;
            int r0 = 0, r1 = 0, r2 = 0;
            #pragma unroll 1
            for (int j = 0; j < cnt; ++j) {
                unsigned long long a = sk[w][j];
                r0 += (int)(a < k0); r1 += (int)(a < k1); r2 += (int)(a < k2);
            }
            if (r0 < KK && lane < cnt) {
                int idx = (int)(unsigned int)(k0 & 0xffffffffull);
                idcs[cell*KK + r0] = idx;  wk[cell*KK + r0] = width[idx];
            }
            if (r1 < KK && lane + 64 < cnt) {
                int idx = (int)(unsigned int)(k1 & 0xffffffffull);
                idcs[cell*KK + r1] = idx;  wk[cell*KK + r1] = width[idx];
            }
            if (r2 < KK && lane + 128 < cnt) {
                int idx = (int)(unsigned int)(k2 & 0xffffffffull);
                idcs[cell*KK + r2] = idx;  wk[cell*KK + r2] = width[idx];
            }
        }
    } else {
        if (lane == 0) {                 // exactness fallback (statistically never)
            float bd[KK]; int bi[KK];
            for (int k = 0; k < KK; ++k) { bd[k] = 3.4e38f; bi[k] = 0; }
            for (int n = 0; n < NS; ++n) {
                float dx = c0 - loc[n*2+0];
                float dy = c1 - loc[n*2+1];
                float d = dx*dx + dy*dy;
                if (d < bd[KK-1]) {
                    int p = KK - 1;
                    while (p > 0 && bd[p-1] > d) { bd[p] = bd[p-1]; bi[p] = bi[p-1]; --p; }
                    bd[p] = d; bi[p] = n;
                }
            }
            for (int k = 0; k < KK; ++k) {
                idcs[cell*KK + k] = bi[k];
                wk[cell*KK + k]   = width[bi[k]];
            }
        }
    }
}

// ---------- Kernel 4: render (r11 verbatim — numerics frozen) ----------
// NOTE: sg-loop and softmax arithmetic must not be restructured: mink feeds
// z = 1e5/(1e-8+mink) whose softmax is ulp-sensitive at stroke intersections
// (r9/r10 failures). Memory-path changes only.
__global__ void __launch_bounds__(256, 4) render_kernel(const float* __restrict__ sdata,
                                                        const float4* __restrict__ ctab,
                                                        const int* __restrict__ idcs,
                                                        const float* __restrict__ wk,
                                                        float* __restrict__ out) {
    int tt0 = threadIdx.x, lane = tt0 & 63, wq = tt0 >> 6;
    int x = blockIdx.x * 16 + ((wq & 1) << 3) + (lane & 7);   // wave = 8x8 pixel tile
    int y = blockIdx.y * 16 + ((wq >> 1) << 3) + (lane >> 3);
    const float df = 512.0f / 511.0f;        // linspace(0,512,512) step in fp32
    float p0 = (float)y * df;                // H-coordinate
    float p1 = (float)x * df;                // W-coordinate
    int cy = (y * 51) >> 8;                  // floor(y*102/512), exact vs fp32 ref
    int cx = (x * 51) >> 8;

    const int4* mip = (const int4*)(idcs + (cy * HC + cx) * KK);
    int4 m0 = mip[0], m1 = mip[1], m2 = mip[2], m3 = mip[3], m4 = mip[4];
    int idxs[KK] = {m0.x,m0.y,m0.z,m0.w, m1.x,m1.y,m1.z,m1.w, m2.x,m2.y,m2.z,m2.w,
                    m3.x,m3.y,m3.z,m3.w, m4.x,m4.y,m4.z,m4.w};

    // jax.image.resize linear: half-pixel centers + edge-normalized == clamped bilinear
    const float sc = 102.0f / 512.0f;        // exact in fp32
    float iny = ((float)y + 0.5f) * sc - 0.5f;
    float inx = ((float)x + 0.5f) * sc - 0.5f;
    float y0f = floorf(iny), x0f = floorf(inx);
    float fy = iny - y0f, fx = inx - x0f;
    int y0 = min(max((int)y0f, 0), HC - 1);
    int y1 = min(max((int)y0f + 1, 0), HC - 1);
    int x0 = min(max((int)x0f, 0), HC - 1);
    int x1 = min(max((int)x0f + 1, 0), HC - 1);
    const float* w00 = wk + (y0 * HC + x0) * KK;
    const float* w01 = wk + (y0 * HC + x1) * KK;
    const float* w10 = wk + (y1 * HC + x0) * KK;
    const float* w11 = wk + (y1 * HC + x1) * KK;

    float m = -INFINITY, s = 0.0f;
    float a0 = 0.0f, a1 = 0.0f, a2 = 0.0f, wa = 0.0f;
    float D = INFINITY;

    #pragma unroll 4
    for (int k = 0; k < KK; ++k) {
        const float4* sp = (const float4*)(sdata + idxs[k] * 32);
        float4 f0 = sp[0], f1 = sp[1], f2 = sp[2], f3 = sp[3], f4 = sp[4];
        float4 i0 = sp[5], i1 = sp[6], i2 = sp[7];
        float4 cw = ctab[idxs[k]];
        float qx[10] = {f0.x, f0.z, f1.x, f1.z, f2.x, f2.z, f3.x, f3.z, f4.x, f4.z};
        float qy[10] = {f0.y, f0.w, f1.y, f1.w, f2.y, f2.w, f3.y, f3.w, f4.y, f4.w};
        float iv[9]  = {i0.x, i0.y, i0.z, i0.w, i1.x, i1.y, i1.z, i1.w, i2.x};
        float mink = INFINITY;
        #pragma unroll
        for (int sg = 0; sg < 9; ++sg) {
            float ax = qx[sg], ay = qy[sg];
            float bx = qx[sg+1] - ax, by = qy[sg+1] - ay;
            float pax = p0 - ax, pay = p1 - ay;
            float dot = bx * pax + by * pay;
            float tt = dot * iv[sg];
            tt = fminf(fmaxf(tt, 0.0f), 1.0f);
            float ccx = ax + tt * bx, ccy = ay + tt * by;
            float ddx = p0 - ccx, ddy = p1 - ccy;
            float d = ddx * ddx + ddy * ddy;
            mink = fminf(mink, d);
        }
        D = fminf(D, mink);
        float z = 100000.0f / (1e-8f + mink);    // IEEE div: exponent is rounding-sensitive
        float wkv = (1.0f - fy) * ((1.0f - fx) * w00[k] + fx * w01[k])
                  +          fy * ((1.0f - fx) * w10[k] + fx * w11[k]);
        // branchless online softmax (== subtract-max softmax, exp(0)==1 exactly)
        float nm  = fmaxf(m, z);
        float scl = __expf(m - nm);              // m=-inf first iter -> 0
        float e   = __expf(z - nm);
        s  = s  * scl + e;
        a0 = a0 * scl + cw.x * e;
        a1 = a1 * scl + cw.y * e;
        a2 = a2 * scl + cw.z * e;
        wa = wa * scl + wkv  * e;
        m = nm;
    }
    float inv = 1.0f / s;
    float bs = wa * inv;
    float msk = 1.0f / (1.0f + __expf(-(bs - D)));   // sigmoid
    float o0 = a0 * inv * msk + (1.0f - msk) * 0.5f;
    float o1 = a1 * inv * msk + (1.0f - msk) * 0.5f;
    float o2 = a2 * inv * msk + (1.0f - msk) * 0.5f;
    int base = (y * 512 + x) * 3;
    out[base+0] = o0;
    out[base+1] = o1;
    out[base+2] = o2;
}

extern "C" void kernel_launch(void* const* d_in, const int* in_sizes, int n_in,
                              void* d_out, int out_size, void* d_ws, size_t ws_size,
                              hipStream_t stream) {
    const float* cs    = (const float*)d_in[0];  // curve_s (5000,2)
    const float* ce    = (const float*)d_in[1];  // curve_e (5000,2)
    const float* cc    = (const float*)d_in[2];  // curve_c (5000,2)
    const float* color = (const float*)d_in[3];  // color   (5000,3)
    const float* loc   = (const float*)d_in[4];  // location(5000,2)
    const float* width = (const float*)d_in[5];  // width   (5000,1)
    float* out = (float*)d_out;

    char* p = (char*)d_ws;
    float*  sdata    = (float*)p;                 p += NS * 32 * sizeof(float);       // 640000
    float4* ctab     = (float4*)p;                p += NS * sizeof(float4);           // 80000
    int*    idcs     = (int*)p;                   p += (size_t)HC*HC*KK*sizeof(int);  // 832320
    float*  wk       = (float*)p;                 p += (size_t)HC*HC*KK*sizeof(float);// 832320
    int*    binCntP  = (int*)p;                   p += NPB * NBIN*NBIN * sizeof(int); // 81920
    int*    binStart = (int*)p;                   p += 4112;                          // 1025 ints + pad
    float2* sxy      = (float2*)p;                p += NS * sizeof(float2);           // 40000
    int*    sid      = (int*)p;                   /* 20000 */

    prep_kernel   <<<NPB, 256, 0, stream>>>(cs, ce, cc, loc, color, width, sdata, ctab, binCntP);
    scatter_kernel<<<NPB, 256, 0, stream>>>(loc, binCntP, binStart, sxy, sid);
    topk_kernel   <<<(HC*HC)/4, 256, 0, stream>>>(loc, width, sxy, sid, binStart, idcs, wk);
    render_kernel <<<dim3(32, 32), 256, 0, stream>>>(sdata, ctab, idcs, wk, out);
}